// Round 3
// baseline (263.520 us; speedup 1.0000x reference)
//
#include <hip/hip_runtime.h>
#include <math.h>

#define EPSV 1e-12f

constexpr int K_MAX   = 150;   // classes (runtime K must be <= this)
constexpr int CH      = 64;    // channels per block (= lanes per wave)
constexpr int PIX     = 1024;  // pixels per block
constexpr int TILE    = 64;    // pixels per LDS tile
constexpr int NT      = PIX / TILE;   // 16 tiles
constexpr int THREADS = 512;   // 8 waves

// ---------------------------------------------------------------------------
// segsum: block = (pixel-block pb, channel-group cg). Wave lanes = channels.
// LDS tile fv[64ch][64px] (rows padded to 65 -> all accesses 2-way-bank max).
// Scatter: atomicAdd(&bins[label*64 + lane]) -- consecutive addresses,
// conflict-free by construction. Flush: plain stores to partial[pb] (DIRECT)
// or atomics to partial[pb%G] (fallback). cg==0 blocks also histogram counts.
// ---------------------------------------------------------------------------
template<bool DIRECT>
__global__ __launch_bounds__(THREADS) void segsum_kernel(
    const float* __restrict__ feat,     // [B,C,HW]
    const int*   __restrict__ labels,   // [B,HW]
    const int*   __restrict__ ign_p,
    float*       __restrict__ partial,  // [G][K*C]
    unsigned int* __restrict__ counts,  // [K]
    int B, int C, int HW, int K, int G)
{
    __shared__ float fv[CH][TILE + 1];       // 64 x 65 floats = 16.6 KB
    __shared__ float bins[K_MAX * CH];       // 150*64*4 = 38.4 KB
    __shared__ int   laddr[PIX];             // 4 KB (label*CH or -1)
    __shared__ unsigned int cbins[K_MAX];

    const int tid  = threadIdx.x;
    const int wid  = tid >> 6;
    const int lane = tid & 63;

    const int CG  = C / CH;                  // 4
    const int NPB = HW / PIX;                // 16 per image
    int bid = blockIdx.x;
    int cg  = bid % CG;                      // consecutive blocks share labels
    int pb  = bid / CG;                      // 0 .. B*NPB-1
    int ck  = pb % NPB;
    int b   = pb / NPB;
    const int ig = *ign_p;

    // zero bins (+ count bins)
    for (int i = tid; i < K * CH; i += THREADS) bins[i] = 0.f;
    if (cg == 0) for (int i = tid; i < K; i += THREADS) cbins[i] = 0u;

    // labels -> bin-row byte-free addresses (label*CH), fused count histogram
    const int* lp = labels + (size_t)b * HW + (size_t)ck * PIX;
    for (int i = tid; i < PIX; i += THREADS) {
        int l = lp[i];
        int a = (l == ig) ? 0 : l;
        bool ok = (unsigned)a < (unsigned)K;
        laddr[i] = ok ? a * CH : -1;
        if (cg == 0 && ok) atomicAdd(&cbins[a], 1u);   // after-sync hazard? no:
        // cbins zeroed above by THIS loop's predecessors only if same thread..
    }
    // NOTE: cbins zero + histogram ordering is enforced below by re-doing the
    // histogram AFTER the first barrier would be wasteful; instead we rely on:
    // zero loop and histogram loop are both executed by all threads, but a
    // thread may histogram before another thread zeroes. Fix: do histogram
    // after the first __syncthreads using laddr.
    __syncthreads();
    if (cg == 0) {
        for (int i = tid; i < PIX; i += THREADS) {
            int la = laddr[i];
            if (la >= 0) atomicAdd(&cbins[la >> 6], 0u);  // placeholder no-op
        }
    }
    // (real histogram done below; see counts flush)

    // staging thread mapping: row = (tid>>4) (0..31) + 32*pass, colquad = tid&15
    const int srow = tid >> 4;               // 0..31
    const int scol = (tid & 15) * 4;         // 0..60
    const float* fbase = feat + ((size_t)b * C + (size_t)cg * CH) * HW
                              + (size_t)ck * PIX;

    float4 pf0, pf1;
    auto issue = [&](int t) {
        const float* p0 = fbase + (size_t)srow * HW + t * TILE + scol;
        pf0 = *reinterpret_cast<const float4*>(p0);
        pf1 = *reinterpret_cast<const float4*>(p0 + (size_t)32 * HW);
    };

    issue(0);
    __syncthreads();   // zeros + laddr visible

    for (int t = 0; t < NT; ++t) {
        // commit tile t (8 scalar LDS stores: rows padded 65 -> 2-way banks)
        {
            float* d0 = &fv[srow][scol];
            d0[0] = pf0.x; d0[1] = pf0.y; d0[2] = pf0.z; d0[3] = pf0.w;
            float* d1 = &fv[srow + 32][scol];
            d1[0] = pf1.x; d1[1] = pf1.y; d1[2] = pf1.z; d1[3] = pf1.w;
        }
        __syncthreads();
        if (t + 1 < NT) issue(t + 1);        // loads in flight during consume

        const int base = t * TILE + wid * 8; // 8 waves x 8 pixels = 64
        #pragma unroll
        for (int i = 0; i < 8; ++i) {
            int   la = laddr[base + i];      // wave-uniform broadcast read
            float f  = fv[lane][wid * 8 + i];// banks (lane + p) % 32 -> 2-way
            if (la >= 0) atomicAdd(&bins[la + lane], f);  // consecutive addrs
        }
        __syncthreads();
    }

    // flush bins -> partial
    {
        size_t g    = DIRECT ? (size_t)pb : (size_t)(pb % G);
        float* dst  = partial + g * (size_t)K * C + (size_t)cg * CH;
        for (int i = tid; i < K * CH; i += THREADS) {
            int k = i >> 6, c = i & 63;
            float v = bins[i];
            if (DIRECT) dst[(size_t)k * C + c] = v;
            else if (v != 0.f) atomicAdd(&dst[(size_t)k * C + c], v);
        }
    }
    // counts flush (cg==0): histogram from laddr now (cbins zeroed pre-barrier)
    if (cg == 0) {
        for (int i = tid; i < PIX; i += THREADS) {
            int la = laddr[i];
            if (la >= 0) atomicAdd(&cbins[la >> 6], 1u);
        }
        __syncthreads();
        for (int i = tid; i < K; i += THREADS)
            if (cbins[i]) atomicAdd(&counts[i], cbins[i]);
    }
}

// ---------------------------------------------------------------------------
// rowloss: block k. Reduce partial over G groups -> prototype row, normalize,
// then 4 waves sweep text rows (fused text-norm + dot + online logsumexp).
// ---------------------------------------------------------------------------
__global__ __launch_bounds__(256) void rowloss_kernel(
    const float* __restrict__ partial,    // [G][K*C]
    const unsigned int* __restrict__ counts,
    const float* __restrict__ text,       // [K,C]
    float* __restrict__ loss_acc,
    int K, int C, int G)
{
    int k = blockIdx.x;
    unsigned cnt = counts[k];
    if (cnt == 0) return;

    __shared__ float ph_lds[256];
    __shared__ float red[8];
    __shared__ float wred[4 * 3];

    int tid  = threadIdx.x;
    int wid  = tid >> 6;
    int lane = tid & 63;

    // reduce partial: thread tid owns channel tid (C == 256 == blockDim)
    const size_t KC = (size_t)K * C;
    const float* pp = partial + (size_t)k * C + tid;
    float a0 = 0.f, a1 = 0.f, a2 = 0.f, a3 = 0.f;
    int g = 0;
    for (; g + 4 <= G; g += 4) {
        a0 += pp[(size_t)(g + 0) * KC];
        a1 += pp[(size_t)(g + 1) * KC];
        a2 += pp[(size_t)(g + 2) * KC];
        a3 += pp[(size_t)(g + 3) * KC];
    }
    for (; g < G; ++g) a0 += pp[(size_t)g * KC];
    float p = ((a0 + a1) + (a2 + a3)) / (float)cnt;

    float v = p * p;
    #pragma unroll
    for (int o = 32; o > 0; o >>= 1) v += __shfl_down(v, o);
    if (lane == 0) red[wid] = v;
    __syncthreads();
    if (tid == 0) {
        float s = red[0] + red[1] + red[2] + red[3];
        red[4] = 1.0f / fmaxf(sqrtf(s), EPSV);
    }
    __syncthreads();
    ph_lds[tid] = p * red[4];
    __syncthreads();

    float m = -INFINITY, s = 0.f, simkk = 0.f;
    for (int j = wid; j < K; j += 4) {
        if (counts[j] == 0) continue;
        const float* tp = text + (size_t)j * C;
        float d = 0.f, tsq = 0.f;
        for (int cc = lane; cc < C; cc += 64) {
            float t = tp[cc];
            d   = fmaf(ph_lds[cc], t, d);
            tsq = fmaf(t, t, tsq);
        }
        #pragma unroll
        for (int o = 32; o > 0; o >>= 1) {
            d   += __shfl_down(d, o);
            tsq += __shfl_down(tsq, o);
        }
        if (lane == 0) {
            float sim = d * (1.0f / fmaxf(sqrtf(tsq), EPSV)) * 10.0f; // /TEMP
            if (j == k) simkk = sim;
            if (sim > m) { s = s * expf(m - sim) + 1.f; m = sim; }
            else         { s += expf(sim - m); }
        }
    }
    if (lane == 0) { wred[wid*3+0] = m; wred[wid*3+1] = s; wred[wid*3+2] = simkk; }
    __syncthreads();
    if (tid == 0) {
        float M = fmaxf(fmaxf(wred[0], wred[3]), fmaxf(wred[6], wred[9]));
        float S = 0.f, skk = 0.f;
        #pragma unroll
        for (int w = 0; w < 4; ++w) {
            float mw = wred[w*3+0];
            float sw = wred[w*3+1];
            S += (mw == -INFINITY) ? 0.f : sw * expf(mw - M);
            skk += wred[w*3+2];
        }
        atomicAdd(loss_acc, M + logf(S) - skk);   // -logp[k][k]
    }
}

// ---------------------------------------------------------------------------
// finalize
// ---------------------------------------------------------------------------
__global__ __launch_bounds__(256) void finalize_kernel(
    const unsigned int* __restrict__ counts,
    const float* __restrict__ loss_acc,
    float* __restrict__ out, int K)
{
    __shared__ float red[4];
    int tid = threadIdx.x, wid = tid >> 6, lane = tid & 63;
    float v = (tid < K && counts[tid] > 0u) ? 1.f : 0.f;
    #pragma unroll
    for (int o = 32; o > 0; o >>= 1) v += __shfl_down(v, o);
    if (lane == 0) red[wid] = v;
    __syncthreads();
    if (tid == 0) {
        float nv = red[0] + red[1] + red[2] + red[3];
        float loss = loss_acc[0] / fmaxf(nv, 1.f);
        out[0] = (nv > 1.f) ? loss : 0.f;
    }
}

extern "C" void kernel_launch(void* const* d_in, const int* in_sizes, int n_in,
                              void* d_out, int out_size, void* d_ws, size_t ws_size,
                              hipStream_t stream) {
    const float* feat   = (const float*)d_in[0];
    const int*   labels = (const int*)d_in[1];
    const float* text   = (const float*)d_in[2];
    const int*   ign    = (const int*)d_in[3];

    const int B  = 8;
    const int N  = in_sizes[1];          // 131072
    const int HW = N / B;                // 16384
    const int C  = in_sizes[0] / N;      // 256
    const int K  = in_sizes[2] / C;      // 150

    const int NPB = B * (HW / PIX);      // 128 pixel-blocks
    const int CG  = C / CH;              // 4
    const size_t KC = (size_t)K * C;

    // choose flush mode by workspace size
    int G; bool direct;
    if (ws_size >= ((size_t)NPB * KC + K + 4) * 4)      { G = NPB; direct = true; }
    else if (ws_size >= ((size_t)8 * KC + K + 4) * 4)   { G = 8;   direct = false; }
    else                                                { G = 1;   direct = false; }

    float*        partial  = (float*)d_ws;                    // [G][KC]
    unsigned int* counts   = (unsigned int*)(partial + (size_t)G * KC);
    float*        loss_acc = (float*)(counts + K);

    hipMemsetAsync(counts, 0, (K + 1) * sizeof(unsigned int), stream);
    if (!direct)
        hipMemsetAsync(partial, 0, (size_t)G * KC * sizeof(float), stream);

    int grid = NPB * CG;                 // 512 blocks, 512 threads
    if (direct)
        segsum_kernel<true><<<grid, THREADS, 0, stream>>>(
            feat, labels, ign, partial, counts, B, C, HW, K, G);
    else
        segsum_kernel<false><<<grid, THREADS, 0, stream>>>(
            feat, labels, ign, partial, counts, B, C, HW, K, G);

    rowloss_kernel<<<K, 256, 0, stream>>>(partial, counts, text, loss_acc, K, C, G);

    finalize_kernel<<<1, 256, 0, stream>>>(counts, loss_acc, (float*)d_out, K);
}

// Round 4
// 115.112 us; speedup vs baseline: 2.2893x; 2.2893x over previous
//
#include <hip/hip_runtime.h>
#include <math.h>

#define EPSV 1e-12f

typedef __attribute__((ext_vector_type(8))) short short8;
typedef __attribute__((ext_vector_type(4))) float f32x4;

constexpr int K_CLS_MAX = 150;
constexpr int MT    = 10;            // M-tiles of 16 -> K_PAD = 160 class rows
constexpr int K_PAD = MT * 16;
constexpr int CPB   = 64;            // channels per block (4 ct tiles of 16)
constexpr int CHUNK = 128;           // pixels per staged chunk
constexpr int PBPX  = 2048;          // pixels per pixel-block
constexpr int NCHK  = PBPX / CHUNK;  // 16 chunks
constexpr int NPB   = 64;            // pixel-blocks (131072/2048)
constexpr int THR   = 512;           // 8 waves
constexpr int LROW  = 136;           // LDS B-row stride in shorts (272 B, 16B-aligned)

__device__ __forceinline__ unsigned short f2bf(float f) {
    unsigned u = __builtin_bit_cast(unsigned, f);
    return (unsigned short)((u + 0x7FFFu + ((u >> 16) & 1u)) >> 16);  // RNE
}

// ---------------------------------------------------------------------------
// protomm: segment-sum via one-hot MFMA GEMM.
// OUT[class 160][ch] += Sum_px onehot(label[px]==class) * feat[ch][px]
// A-frag (16x32): lane l: row=l&15 (class-in-tile), k=(l>>4)*8+j (pixel)
// B-frag (32x16): lane l: col=l&15 (channel),       k=(l>>4)*8+j (pixel)
// C/D:            lane l: col=l&15 (channel), row=(l>>4)*4+reg (class) [m89]
// ---------------------------------------------------------------------------
__global__ __launch_bounds__(THR) void protomm_kernel(
    const float* __restrict__ feat,     // [B,C,HW]
    const int*   __restrict__ labels,   // [B,HW]
    const int*   __restrict__ ign_p,
    float*       __restrict__ partial,  // [NPB][K_PAD][C]
    int C, int HW)
{
    __shared__ unsigned short Bf[CPB * LROW];   // 17.4 KB bf16 feature tile
    __shared__ int   labL[CHUNK];               // 512 B
    __shared__ float fscr[4][K_PAD * 16];       // 40 KB flush scratch

    const int tid   = threadIdx.x;
    const int w     = tid >> 6;
    const int l     = tid & 63;
    const int ct    = w & 3;        // N-slice (16 channels)
    const int kh    = w >> 2;       // k-half (ksteps 2kh, 2kh+1)
    const int rowid = l & 15;
    const int g     = l >> 4;

    const int bid = blockIdx.x;
    const int cg  = bid & 3;        // channel group (64 ch)
    const int pb  = bid >> 2;       // pixel-block 0..63
    const int b   = pb >> 3;        // image
    const int px0 = (pb & 7) * PBPX;
    const int ig  = *ign_p;

    // staging mapping: thread = (chp 0..15, q 0..31); ch = chp + 16*i
    const int q   = tid & 31;
    const int chp = tid >> 5;
    const float* fb = feat + ((size_t)(b * C + cg * CPB + chp)) * HW + px0 + 4 * q;
    const int*   lb = labels + (size_t)b * HW + px0;

    f32x4 acc[MT];
    #pragma unroll
    for (int m = 0; m < MT; ++m) acc[m] = (f32x4){0.f, 0.f, 0.f, 0.f};

    float4 pf0, pf1, pf2, pf3;
    int4   plab;
    auto issue = [&](int ck) {
        const float* p = fb + ck * CHUNK;
        pf0 = *reinterpret_cast<const float4*>(p);
        pf1 = *reinterpret_cast<const float4*>(p + (size_t)16 * HW);
        pf2 = *reinterpret_cast<const float4*>(p + (size_t)32 * HW);
        pf3 = *reinterpret_cast<const float4*>(p + (size_t)48 * HW);
        if (tid < 32)
            plab = *reinterpret_cast<const int4*>(lb + ck * CHUNK + 4 * tid);
    };

    issue(0);

    for (int ck = 0; ck < NCHK; ++ck) {
        __syncthreads();                       // prev MFMA done with Bf/labL
        // commit staged chunk: f32 -> bf16 into Bf, labels into labL
        {
            float4 v[4] = {pf0, pf1, pf2, pf3};
            #pragma unroll
            for (int i = 0; i < 4; ++i) {
                unsigned* dst = reinterpret_cast<unsigned*>(
                    &Bf[(chp + 16 * i) * LROW + 4 * q]);
                dst[0] = (unsigned)f2bf(v[i].x) | ((unsigned)f2bf(v[i].y) << 16);
                dst[1] = (unsigned)f2bf(v[i].z) | ((unsigned)f2bf(v[i].w) << 16);
            }
            if (tid < 32) {
                int4 lv = plab;
                lv.x = (lv.x == ig) ? 0 : lv.x;
                lv.y = (lv.y == ig) ? 0 : lv.y;
                lv.z = (lv.z == ig) ? 0 : lv.z;
                lv.w = (lv.w == ig) ? 0 : lv.w;
                *reinterpret_cast<int4*>(&labL[4 * tid]) = lv;
            }
        }
        __syncthreads();
        if (ck + 1 < NCHK) issue(ck + 1);      // HBM latency hides under MFMA

        #pragma unroll
        for (int kk = 0; kk < 2; ++kk) {
            const int ks = 2 * kh + kk;
            const int* lp = &labL[ks * 32 + g * 8];   // 16-lane broadcast reads
            const int la0 = lp[0], la1 = lp[1], la2 = lp[2], la3 = lp[3];
            const int la4 = lp[4], la5 = lp[5], la6 = lp[6], la7 = lp[7];
            const short8 bfrag = *reinterpret_cast<const short8*>(
                &Bf[(ct * 16 + rowid) * LROW + ks * 32 + g * 8]);
            #pragma unroll
            for (int m = 0; m < MT; ++m) {
                const int tgt = m * 16 + rowid;
                unsigned w0 = (la0 == tgt ? 0x3F80u : 0u) | (la1 == tgt ? 0x3F800000u : 0u);
                unsigned w1 = (la2 == tgt ? 0x3F80u : 0u) | (la3 == tgt ? 0x3F800000u : 0u);
                unsigned w2 = (la4 == tgt ? 0x3F80u : 0u) | (la5 == tgt ? 0x3F800000u : 0u);
                unsigned w3 = (la6 == tgt ? 0x3F80u : 0u) | (la7 == tgt ? 0x3F800000u : 0u);
                uint4 aw = make_uint4(w0, w1, w2, w3);
                short8 afrag = __builtin_bit_cast(short8, aw);
                acc[m] = __builtin_amdgcn_mfma_f32_16x16x32_bf16(afrag, bfrag, acc[m], 0, 0, 0);
            }
        }
    }

    // flush: sum the two k-halves via LDS, then plain stores to partial
    __syncthreads();
    if (kh == 1) {
        #pragma unroll
        for (int m = 0; m < MT; ++m)
            #pragma unroll
            for (int r = 0; r < 4; ++r)
                fscr[ct][(m * 16 + g * 4 + r) * 16 + rowid] = acc[m][r];
    }
    __syncthreads();
    if (kh == 0) {
        float* dst = partial + (size_t)pb * K_PAD * C + cg * CPB + ct * 16 + rowid;
        #pragma unroll
        for (int m = 0; m < MT; ++m)
            #pragma unroll
            for (int r = 0; r < 4; ++r) {
                const int cls = m * 16 + g * 4 + r;
                dst[(size_t)cls * C] = acc[m][r] + fscr[ct][cls * 16 + rowid];
            }
    }
}

// ---------------------------------------------------------------------------
// counts: label histogram
// ---------------------------------------------------------------------------
__global__ __launch_bounds__(256) void counts_kernel(
    const int* __restrict__ labels, const int* __restrict__ ign_p,
    unsigned int* __restrict__ counts, int N, int K)
{
    __shared__ unsigned int cbins[160];
    const int tid = threadIdx.x;
    for (int i = tid; i < 160; i += 256) cbins[i] = 0u;
    __syncthreads();
    const int ig = *ign_p;
    const int4* l4 = reinterpret_cast<const int4*>(labels);
    const int n4 = N / 4;
    for (int i = blockIdx.x * 256 + tid; i < n4; i += gridDim.x * 256) {
        int4 v = l4[i];
        int a0 = (v.x == ig) ? 0 : v.x;
        int a1 = (v.y == ig) ? 0 : v.y;
        int a2 = (v.z == ig) ? 0 : v.z;
        int a3 = (v.w == ig) ? 0 : v.w;
        if ((unsigned)a0 < (unsigned)K) atomicAdd(&cbins[a0], 1u);
        if ((unsigned)a1 < (unsigned)K) atomicAdd(&cbins[a1], 1u);
        if ((unsigned)a2 < (unsigned)K) atomicAdd(&cbins[a2], 1u);
        if ((unsigned)a3 < (unsigned)K) atomicAdd(&cbins[a3], 1u);
    }
    __syncthreads();
    for (int i = tid; i < K; i += 256)
        if (cbins[i]) atomicAdd(&counts[i], cbins[i]);
}

// ---------------------------------------------------------------------------
// rowloss: block k reduces partial over NPB slots -> prototype, normalizes,
// then 4 waves sweep text rows (fused text-norm + dot + online logsumexp).
// ---------------------------------------------------------------------------
__global__ __launch_bounds__(256) void rowloss_kernel(
    const float* __restrict__ partial,    // [NPB][K_PAD][C]
    const unsigned int* __restrict__ counts,
    const float* __restrict__ text,       // [K,C]
    float* __restrict__ loss_acc,
    int K, int C, int G)
{
    int k = blockIdx.x;
    unsigned cnt = counts[k];
    if (cnt == 0) return;

    __shared__ float ph_lds[256];
    __shared__ float red[8];
    __shared__ float wred[4 * 3];

    int tid  = threadIdx.x;
    int wid  = tid >> 6;
    int lane = tid & 63;

    const size_t stride = (size_t)K_PAD * C;
    const float* pp = partial + (size_t)k * C + tid;   // C == 256 == blockDim
    float a0 = 0.f, a1 = 0.f, a2 = 0.f, a3 = 0.f, a4 = 0.f, a5 = 0.f, a6 = 0.f, a7 = 0.f;
    for (int g = 0; g + 8 <= G; g += 8) {
        a0 += pp[(g + 0) * stride]; a1 += pp[(g + 1) * stride];
        a2 += pp[(g + 2) * stride]; a3 += pp[(g + 3) * stride];
        a4 += pp[(g + 4) * stride]; a5 += pp[(g + 5) * stride];
        a6 += pp[(g + 6) * stride]; a7 += pp[(g + 7) * stride];
    }
    float p = (((a0 + a1) + (a2 + a3)) + ((a4 + a5) + (a6 + a7))) / (float)cnt;

    float v = p * p;
    #pragma unroll
    for (int o = 32; o > 0; o >>= 1) v += __shfl_down(v, o);
    if (lane == 0) red[wid] = v;
    __syncthreads();
    if (tid == 0) {
        float s = red[0] + red[1] + red[2] + red[3];
        red[4] = 1.0f / fmaxf(sqrtf(s), EPSV);
    }
    __syncthreads();
    ph_lds[tid] = p * red[4];
    __syncthreads();

    float m = -INFINITY, s = 0.f, simkk = 0.f;
    for (int j = wid; j < K; j += 4) {
        if (counts[j] == 0) continue;
        const float* tp = text + (size_t)j * C;
        float d = 0.f, tsq = 0.f;
        for (int cc = lane; cc < C; cc += 64) {
            float t = tp[cc];
            d   = fmaf(ph_lds[cc], t, d);
            tsq = fmaf(t, t, tsq);
        }
        #pragma unroll
        for (int o = 32; o > 0; o >>= 1) {
            d   += __shfl_down(d, o);
            tsq += __shfl_down(tsq, o);
        }
        if (lane == 0) {
            float sim = d * (1.0f / fmaxf(sqrtf(tsq), EPSV)) * 10.0f; // /TEMP
            if (j == k) simkk = sim;
            if (sim > m) { s = s * expf(m - sim) + 1.f; m = sim; }
            else         { s += expf(sim - m); }
        }
    }
    if (lane == 0) { wred[wid*3+0] = m; wred[wid*3+1] = s; wred[wid*3+2] = simkk; }
    __syncthreads();
    if (tid == 0) {
        float M = fmaxf(fmaxf(wred[0], wred[3]), fmaxf(wred[6], wred[9]));
        float S = 0.f, skk = 0.f;
        #pragma unroll
        for (int w = 0; w < 4; ++w) {
            float mw = wred[w*3+0];
            float sw = wred[w*3+1];
            S += (mw == -INFINITY) ? 0.f : sw * expf(mw - M);
            skk += wred[w*3+2];
        }
        atomicAdd(loss_acc, M + logf(S) - skk);   // -logp[k][k]
    }
}

// ---------------------------------------------------------------------------
// finalize
// ---------------------------------------------------------------------------
__global__ __launch_bounds__(256) void finalize_kernel(
    const unsigned int* __restrict__ counts,
    const float* __restrict__ loss_acc,
    float* __restrict__ out, int K)
{
    __shared__ float red[4];
    int tid = threadIdx.x, wid = tid >> 6, lane = tid & 63;
    float v = (tid < K && counts[tid] > 0u) ? 1.f : 0.f;
    #pragma unroll
    for (int o = 32; o > 0; o >>= 1) v += __shfl_down(v, o);
    if (lane == 0) red[wid] = v;
    __syncthreads();
    if (tid == 0) {
        float nv = red[0] + red[1] + red[2] + red[3];
        float loss = loss_acc[0] / fmaxf(nv, 1.f);
        out[0] = (nv > 1.f) ? loss : 0.f;
    }
}

extern "C" void kernel_launch(void* const* d_in, const int* in_sizes, int n_in,
                              void* d_out, int out_size, void* d_ws, size_t ws_size,
                              hipStream_t stream) {
    const float* feat   = (const float*)d_in[0];
    const int*   labels = (const int*)d_in[1];
    const float* text   = (const float*)d_in[2];
    const int*   ign    = (const int*)d_in[3];

    const int B  = 8;
    const int N  = in_sizes[1];          // 131072
    const int HW = N / B;                // 16384
    const int C  = in_sizes[0] / N;      // 256
    const int K  = in_sizes[2] / C;      // 150

    // workspace: partial [NPB][K_PAD][C] f32 (fully overwritten), counts, loss
    float*        partial  = (float*)d_ws;
    unsigned int* counts   = (unsigned int*)(partial + (size_t)NPB * K_PAD * C);
    float*        loss_acc = (float*)(counts + K);

    hipMemsetAsync(counts, 0, (K + 1) * sizeof(unsigned int), stream);

    protomm_kernel<<<NPB * 4, THR, 0, stream>>>(feat, labels, ign, partial, C, HW);

    counts_kernel<<<256, 256, 0, stream>>>(labels, ign, counts, N, K);

    rowloss_kernel<<<K, 256, 0, stream>>>(partial, counts, text, loss_acc, K, C, NPB);

    finalize_kernel<<<1, 256, 0, stream>>>(counts, loss_acc, (float*)d_out, K);
}

// Round 5
// 72.508 us; speedup vs baseline: 3.6343x; 1.5876x over previous
//
#include <hip/hip_runtime.h>
#include <math.h>

#define EPSV 1e-12f

typedef __attribute__((ext_vector_type(8))) short short8;
typedef __attribute__((ext_vector_type(4))) float f32x4;

constexpr int MT    = 10;            // M-tiles of 16 -> K_PAD = 160 class rows
constexpr int K_PAD = MT * 16;
constexpr int CPB   = 64;            // channels per block (4 ct tiles of 16)
constexpr int CHUNK = 128;           // pixels per staged chunk
constexpr int PBPX  = 2048;          // pixels per pixel-block
constexpr int NCHK  = PBPX / CHUNK;  // 16 chunks
constexpr int NPB   = 64;            // pixel-blocks (131072/2048)
constexpr int THR   = 512;           // 8 waves
constexpr int LROW  = 136;           // LDS B-row stride in shorts

__device__ __forceinline__ unsigned short f2bf(float f) {
    unsigned u = __builtin_bit_cast(unsigned, f);
    return (unsigned short)((u + 0x7FFFu + ((u >> 16) & 1u)) >> 16);  // RNE
}

// ---------------------------------------------------------------------------
// protomm: segment-sum via one-hot MFMA GEMM (unchanged from r4).
// ---------------------------------------------------------------------------
__global__ __launch_bounds__(THR) void protomm_kernel(
    const float* __restrict__ feat,     // [B,C,HW]
    const int*   __restrict__ labels,   // [B,HW]
    const int*   __restrict__ ign_p,
    float*       __restrict__ partial,  // [NPB][K_PAD][C]
    int C, int HW)
{
    __shared__ unsigned short Bf[CPB * LROW];
    __shared__ int   labL[CHUNK];
    __shared__ float fscr[4][K_PAD * 16];

    const int tid   = threadIdx.x;
    const int w     = tid >> 6;
    const int l     = tid & 63;
    const int ct    = w & 3;
    const int kh    = w >> 2;
    const int rowid = l & 15;
    const int g     = l >> 4;

    const int bid = blockIdx.x;
    const int cg  = bid & 3;
    const int pb  = bid >> 2;
    const int b   = pb >> 3;
    const int px0 = (pb & 7) * PBPX;
    const int ig  = *ign_p;

    const int q   = tid & 31;
    const int chp = tid >> 5;
    const float* fb = feat + ((size_t)(b * C + cg * CPB + chp)) * HW + px0 + 4 * q;
    const int*   lb = labels + (size_t)b * HW + px0;

    f32x4 acc[MT];
    #pragma unroll
    for (int m = 0; m < MT; ++m) acc[m] = (f32x4){0.f, 0.f, 0.f, 0.f};

    float4 pf0, pf1, pf2, pf3;
    int4   plab;
    auto issue = [&](int ck) {
        const float* p = fb + ck * CHUNK;
        pf0 = *reinterpret_cast<const float4*>(p);
        pf1 = *reinterpret_cast<const float4*>(p + (size_t)16 * HW);
        pf2 = *reinterpret_cast<const float4*>(p + (size_t)32 * HW);
        pf3 = *reinterpret_cast<const float4*>(p + (size_t)48 * HW);
        if (tid < 32)
            plab = *reinterpret_cast<const int4*>(lb + ck * CHUNK + 4 * tid);
    };

    issue(0);

    for (int ck = 0; ck < NCHK; ++ck) {
        __syncthreads();
        {
            float4 v[4] = {pf0, pf1, pf2, pf3};
            #pragma unroll
            for (int i = 0; i < 4; ++i) {
                unsigned* dst = reinterpret_cast<unsigned*>(
                    &Bf[(chp + 16 * i) * LROW + 4 * q]);
                dst[0] = (unsigned)f2bf(v[i].x) | ((unsigned)f2bf(v[i].y) << 16);
                dst[1] = (unsigned)f2bf(v[i].z) | ((unsigned)f2bf(v[i].w) << 16);
            }
            if (tid < 32) {
                int4 lv = plab;
                lv.x = (lv.x == ig) ? 0 : lv.x;
                lv.y = (lv.y == ig) ? 0 : lv.y;
                lv.z = (lv.z == ig) ? 0 : lv.z;
                lv.w = (lv.w == ig) ? 0 : lv.w;
                *reinterpret_cast<int4*>(&labL[4 * tid]) = lv;
            }
        }
        __syncthreads();
        if (ck + 1 < NCHK) issue(ck + 1);

        #pragma unroll
        for (int kk = 0; kk < 2; ++kk) {
            const int ks = 2 * kh + kk;
            const int* lp = &labL[ks * 32 + g * 8];
            const int la0 = lp[0], la1 = lp[1], la2 = lp[2], la3 = lp[3];
            const int la4 = lp[4], la5 = lp[5], la6 = lp[6], la7 = lp[7];
            const short8 bfrag = *reinterpret_cast<const short8*>(
                &Bf[(ct * 16 + rowid) * LROW + ks * 32 + g * 8]);
            #pragma unroll
            for (int m = 0; m < MT; ++m) {
                const int tgt = m * 16 + rowid;
                unsigned w0 = (la0 == tgt ? 0x3F80u : 0u) | (la1 == tgt ? 0x3F800000u : 0u);
                unsigned w1 = (la2 == tgt ? 0x3F80u : 0u) | (la3 == tgt ? 0x3F800000u : 0u);
                unsigned w2 = (la4 == tgt ? 0x3F80u : 0u) | (la5 == tgt ? 0x3F800000u : 0u);
                unsigned w3 = (la6 == tgt ? 0x3F80u : 0u) | (la7 == tgt ? 0x3F800000u : 0u);
                uint4 aw = make_uint4(w0, w1, w2, w3);
                short8 afrag = __builtin_bit_cast(short8, aw);
                acc[m] = __builtin_amdgcn_mfma_f32_16x16x32_bf16(afrag, bfrag, acc[m], 0, 0, 0);
            }
        }
    }

    __syncthreads();
    if (kh == 1) {
        #pragma unroll
        for (int m = 0; m < MT; ++m)
            #pragma unroll
            for (int r = 0; r < 4; ++r)
                fscr[ct][(m * 16 + g * 4 + r) * 16 + rowid] = acc[m][r];
    }
    __syncthreads();
    if (kh == 0) {
        float* dst = partial + (size_t)pb * K_PAD * C + cg * CPB + ct * 16 + rowid;
        #pragma unroll
        for (int m = 0; m < MT; ++m)
            #pragma unroll
            for (int r = 0; r < 4; ++r) {
                const int cls = m * 16 + g * 4 + r;
                dst[(size_t)cls * C] = acc[m][r] + fscr[ct][cls * 16 + rowid];
            }
    }
}

// ---------------------------------------------------------------------------
// counts: label histogram
// ---------------------------------------------------------------------------
__global__ __launch_bounds__(256) void counts_kernel(
    const int* __restrict__ labels, const int* __restrict__ ign_p,
    unsigned int* __restrict__ counts, int N, int K)
{
    __shared__ unsigned int cbins[160];
    const int tid = threadIdx.x;
    for (int i = tid; i < 160; i += 256) cbins[i] = 0u;
    __syncthreads();
    const int ig = *ign_p;
    const int4* l4 = reinterpret_cast<const int4*>(labels);
    const int n4 = N / 4;
    for (int i = blockIdx.x * 256 + tid; i < n4; i += gridDim.x * 256) {
        int4 v = l4[i];
        int a0 = (v.x == ig) ? 0 : v.x;
        int a1 = (v.y == ig) ? 0 : v.y;
        int a2 = (v.z == ig) ? 0 : v.z;
        int a3 = (v.w == ig) ? 0 : v.w;
        if ((unsigned)a0 < (unsigned)K) atomicAdd(&cbins[a0], 1u);
        if ((unsigned)a1 < (unsigned)K) atomicAdd(&cbins[a1], 1u);
        if ((unsigned)a2 < (unsigned)K) atomicAdd(&cbins[a2], 1u);
        if ((unsigned)a3 < (unsigned)K) atomicAdd(&cbins[a3], 1u);
    }
    __syncthreads();
    for (int i = tid; i < K; i += 256)
        if (cbins[i]) atomicAdd(&counts[i], cbins[i]);
}

// ---------------------------------------------------------------------------
// normprep: blocks [0,K_PAD) -> prototype rows (64-slot reduce + normalize),
//           blocks [K_PAD,2*K_PAD) -> text rows (normalize; pad rows zeroed).
// ---------------------------------------------------------------------------
__global__ __launch_bounds__(256) void normprep_kernel(
    const float* __restrict__ partial,    // [NPB][K_PAD][C]
    const unsigned int* __restrict__ counts,
    const float* __restrict__ text,       // [K,C]
    float* __restrict__ proto_n,          // [K_PAD][C]
    float* __restrict__ text_n,           // [K_PAD][C]
    float* __restrict__ vmask,            // [K_PAD] (pre-zeroed)
    int K, int C)
{
    const int bid  = blockIdx.x;
    const int tid  = threadIdx.x;
    const int wid  = tid >> 6;
    const int lane = tid & 63;
    const bool isproto = bid < K_PAD;
    const int  row = isproto ? bid : bid - K_PAD;

    __shared__ float red[5];

    float val = 0.f;
    if (isproto) {
        if (row >= K) return;
        unsigned cnt = counts[row];
        if (cnt == 0) return;                       // vmask stays 0
        const size_t gs = (size_t)K_PAD * C;
        const float* pp = partial + (size_t)row * C + tid;
        float a0 = 0.f, a1 = 0.f, a2 = 0.f, a3 = 0.f;
        float a4 = 0.f, a5 = 0.f, a6 = 0.f, a7 = 0.f;
        #pragma unroll 2
        for (int g = 0; g < NPB; g += 8) {
            a0 += pp[(g + 0) * gs]; a1 += pp[(g + 1) * gs];
            a2 += pp[(g + 2) * gs]; a3 += pp[(g + 3) * gs];
            a4 += pp[(g + 4) * gs]; a5 += pp[(g + 5) * gs];
            a6 += pp[(g + 6) * gs]; a7 += pp[(g + 7) * gs];
        }
        val = (((a0 + a1) + (a2 + a3)) + ((a4 + a5) + (a6 + a7))) / (float)cnt;
    } else {
        if (row >= K) { text_n[(size_t)row * C + tid] = 0.f; return; }
        val = text[(size_t)row * C + tid];
    }

    float v = val * val;
    #pragma unroll
    for (int o = 32; o > 0; o >>= 1) v += __shfl_down(v, o);
    if (lane == 0) red[wid] = v;
    __syncthreads();
    if (tid == 0) {
        float s = red[0] + red[1] + red[2] + red[3];
        red[4] = 1.0f / fmaxf(sqrtf(s), EPSV);
    }
    __syncthreads();
    float out = val * red[4];

    if (isproto) {
        proto_n[(size_t)row * C + tid] = out;
        if (tid == 0) vmask[row] = 1.f;
    } else {
        text_n[(size_t)row * C + tid] = out;
    }
}

// ---------------------------------------------------------------------------
// loss: block k. Stage proto row + vmask in LDS; 4 waves sweep 160 padded
// cols in groups of 4 rows (independent dot chains, arithmetic masking).
// ---------------------------------------------------------------------------
__global__ __launch_bounds__(256) void loss_kernel(
    const float* __restrict__ proto_n,    // [K_PAD][C]
    const float* __restrict__ text_n,     // [K_PAD][C]
    const float* __restrict__ vmask,      // [K_PAD]
    const unsigned int* __restrict__ counts,
    float* __restrict__ loss_acc,
    int K, int C)
{
    const int k = blockIdx.x;
    if (counts[k] == 0) return;

    __shared__ float ph[256];
    __shared__ float vm[K_PAD];
    __shared__ float wred[4 * 3];

    const int tid  = threadIdx.x;
    const int wid  = tid >> 6;
    const int lane = tid & 63;

    ph[tid] = proto_n[(size_t)k * C + tid];
    if (tid < K_PAD) vm[tid] = vmask[tid];
    __syncthreads();

    float m = -INFINITY, s = 0.f, skk = 0.f;
    #pragma unroll 1
    for (int gq = 0; gq < K_PAD / 16; ++gq) {        // 10 groups
        const int j0 = gq * 16 + wid * 4;
        const float* t0 = text_n + (size_t)j0 * C;
        float d0 = 0.f, d1 = 0.f, d2 = 0.f, d3 = 0.f;
        #pragma unroll
        for (int cc = lane; cc < 256; cc += 64) {
            float p = ph[cc];
            d0 = fmaf(p, t0[cc],         d0);
            d1 = fmaf(p, t0[C + cc],     d1);
            d2 = fmaf(p, t0[2 * C + cc], d2);
            d3 = fmaf(p, t0[3 * C + cc], d3);
        }
        #pragma unroll
        for (int o = 32; o > 0; o >>= 1) {
            d0 += __shfl_down(d0, o); d1 += __shfl_down(d1, o);
            d2 += __shfl_down(d2, o); d3 += __shfl_down(d3, o);
        }
        if (lane == 0) {
            float dd[4] = {d0, d1, d2, d3};
            #pragma unroll
            for (int r = 0; r < 4; ++r) {
                int j = j0 + r;
                float v  = vm[j];
                float ms = v * (dd[r] * 10.f) - (1.f - v) * 1e9f;
                if (j == k) skk = ms;
                if (ms > m) { s = s * expf(m - ms) + 1.f; m = ms; }
                else        { s += expf(ms - m); }
            }
        }
    }
    if (lane == 0) { wred[wid*3+0] = m; wred[wid*3+1] = s; wred[wid*3+2] = skk; }
    __syncthreads();
    if (tid == 0) {
        float M = fmaxf(fmaxf(wred[0], wred[3]), fmaxf(wred[6], wred[9]));
        float S = 0.f, SKK = 0.f;
        #pragma unroll
        for (int w = 0; w < 4; ++w) {
            S   += wred[w*3+1] * expf(wred[w*3+0] - M);
            SKK += (wred[w*3+2] != 0.f) ? wred[w*3+2] : 0.f;
        }
        // exactly one wave saw j==k (skk nonzero there, 0 elsewhere; sim_kk==0
        // is astronomically unlikely but harmless: contributes 0 either way)
        atomicAdd(loss_acc, M + logf(S) - SKK);
    }
}

// ---------------------------------------------------------------------------
// finalize
// ---------------------------------------------------------------------------
__global__ __launch_bounds__(256) void finalize_kernel(
    const unsigned int* __restrict__ counts,
    const float* __restrict__ loss_acc,
    float* __restrict__ out, int K)
{
    __shared__ float red[4];
    int tid = threadIdx.x, wid = tid >> 6, lane = tid & 63;
    float v = (tid < K && counts[tid] > 0u) ? 1.f : 0.f;
    #pragma unroll
    for (int o = 32; o > 0; o >>= 1) v += __shfl_down(v, o);
    if (lane == 0) red[wid] = v;
    __syncthreads();
    if (tid == 0) {
        float nv = red[0] + red[1] + red[2] + red[3];
        float loss = loss_acc[0] / fmaxf(nv, 1.f);
        out[0] = (nv > 1.f) ? loss : 0.f;
    }
}

extern "C" void kernel_launch(void* const* d_in, const int* in_sizes, int n_in,
                              void* d_out, int out_size, void* d_ws, size_t ws_size,
                              hipStream_t stream) {
    const float* feat   = (const float*)d_in[0];
    const int*   labels = (const int*)d_in[1];
    const float* text   = (const float*)d_in[2];
    const int*   ign    = (const int*)d_in[3];

    const int B  = 8;
    const int N  = in_sizes[1];          // 131072
    const int HW = N / B;                // 16384
    const int C  = in_sizes[0] / N;      // 256
    const int K  = in_sizes[2] / C;      // 150

    // workspace layout (ws proven >= 19.7 MB in r3): total ~10.82 MB
    float*        partial  = (float*)d_ws;                              // [NPB][K_PAD][C]
    float*        proto_n  = partial + (size_t)NPB * K_PAD * C;         // [K_PAD][C]
    float*        text_n   = proto_n + (size_t)K_PAD * C;               // [K_PAD][C]
    unsigned int* counts   = (unsigned int*)(text_n + (size_t)K_PAD * C); // [K_PAD]
    float*        vmask    = (float*)(counts + K_PAD);                  // [K_PAD]
    float*        loss_acc = vmask + K_PAD;                             // [1]

    hipMemsetAsync(counts, 0, (2 * K_PAD + 1) * sizeof(unsigned int), stream);

    protomm_kernel<<<NPB * 4, THR, 0, stream>>>(feat, labels, ign, partial, C, HW);

    counts_kernel<<<256, 256, 0, stream>>>(labels, ign, counts, N, K);

    normprep_kernel<<<2 * K_PAD, 256, 0, stream>>>(
        partial, counts, text, proto_n, text_n, vmask, K, C);

    loss_kernel<<<K, 256, 0, stream>>>(
        proto_n, text_n, vmask, counts, loss_acc, K, C);

    finalize_kernel<<<1, 256, 0, stream>>>(counts, loss_acc, (float*)d_out, K);
}

// Round 6
// 69.957 us; speedup vs baseline: 3.7669x; 1.0365x over previous
//
#include <hip/hip_runtime.h>
#include <math.h>

#define EPSV 1e-12f

typedef __attribute__((ext_vector_type(8))) short short8;
typedef __attribute__((ext_vector_type(4))) float f32x4;

constexpr int MT    = 10;            // M-tiles of 16 -> K_PAD = 160 class rows
constexpr int K_PAD = MT * 16;
constexpr int CPB   = 64;            // channels per block
constexpr int CHUNK = 128;           // pixels per staged chunk
constexpr int PBPX  = 2048;          // pixels per pixel-block
constexpr int NCHK  = PBPX / CHUNK;  // 16 chunks
constexpr int NPB   = 64;            // pixel-blocks
constexpr int THR   = 512;           // 8 waves
constexpr int LROW  = 136;           // LDS B-row stride in shorts

__device__ __forceinline__ unsigned short f2bf(float f) {
    unsigned u = __builtin_bit_cast(unsigned, f);
    return (unsigned short)((u + 0x7FFFu + ((u >> 16) & 1u)) >> 16);  // RNE
}

// ---------------------------------------------------------------------------
// protomm: segment-sum via one-hot MFMA GEMM, double-buffered LDS
// (one barrier per chunk). cg==0 blocks also record per-class presence
// -> vmask (plain stores of 1.0f; races benign).
// ---------------------------------------------------------------------------
__global__ __launch_bounds__(THR) void protomm_kernel(
    const float* __restrict__ feat,     // [B,C,HW]
    const int*   __restrict__ labels,   // [B,HW]
    const int*   __restrict__ ign_p,
    float*       __restrict__ partial,  // [NPB][K_PAD][C]
    float*       __restrict__ vmask,    // [K_PAD] pre-zeroed
    int C, int HW)
{
    __shared__ unsigned short Bf[2][CPB * LROW];   // 2 x 17.4 KB
    __shared__ int   labL[2][CHUNK];               // 2 x 512 B
    __shared__ float fscr[4][K_PAD * 16];          // 40 KB
    __shared__ unsigned char pres[K_PAD];

    const int tid   = threadIdx.x;
    const int w     = tid >> 6;
    const int l     = tid & 63;
    const int ct    = w & 3;        // N-slice (16 channels)
    const int kh    = w >> 2;       // k-half
    const int rowid = l & 15;
    const int g     = l >> 4;

    const int bid = blockIdx.x;
    const int cg  = bid & 3;
    const int pb  = bid >> 2;
    const int b   = pb >> 3;
    const int px0 = (pb & 7) * PBPX;
    const int ig  = *ign_p;

    const int q   = tid & 31;
    const int chp = tid >> 5;
    const float* fb = feat + ((size_t)(b * C + cg * CPB + chp)) * HW + px0 + 4 * q;
    const int*   lb = labels + (size_t)b * HW + px0;

    if (cg == 0)
        for (int i = tid; i < K_PAD; i += THR) pres[i] = 0;

    f32x4 acc[MT];
    #pragma unroll
    for (int m = 0; m < MT; ++m) acc[m] = (f32x4){0.f, 0.f, 0.f, 0.f};

    float4 pf0, pf1, pf2, pf3;
    int4   plab;
    auto issue = [&](int ck) {
        const float* p = fb + ck * CHUNK;
        pf0 = *reinterpret_cast<const float4*>(p);
        pf1 = *reinterpret_cast<const float4*>(p + (size_t)16 * HW);
        pf2 = *reinterpret_cast<const float4*>(p + (size_t)32 * HW);
        pf3 = *reinterpret_cast<const float4*>(p + (size_t)48 * HW);
        if (tid < 32)
            plab = *reinterpret_cast<const int4*>(lb + ck * CHUNK + 4 * tid);
    };
    auto commit = [&](int buf) {
        float4 v[4] = {pf0, pf1, pf2, pf3};
        #pragma unroll
        for (int i = 0; i < 4; ++i) {
            unsigned* dst = reinterpret_cast<unsigned*>(
                &Bf[buf][(chp + 16 * i) * LROW + 4 * q]);
            dst[0] = (unsigned)f2bf(v[i].x) | ((unsigned)f2bf(v[i].y) << 16);
            dst[1] = (unsigned)f2bf(v[i].z) | ((unsigned)f2bf(v[i].w) << 16);
        }
        if (tid < 32) {
            int4 lv = plab;
            lv.x = (lv.x == ig) ? 0 : lv.x;
            lv.y = (lv.y == ig) ? 0 : lv.y;
            lv.z = (lv.z == ig) ? 0 : lv.z;
            lv.w = (lv.w == ig) ? 0 : lv.w;
            *reinterpret_cast<int4*>(&labL[buf][4 * tid]) = lv;
        }
    };

    issue(0);

    for (int ck = 0; ck < NCHK; ++ck) {
        const int cur = ck & 1;
        commit(cur);                        // waits vmcnt for chunk ck loads
        if (ck + 1 < NCHK) issue(ck + 1);   // next chunk in flight under MFMA
        __syncthreads();                    // one barrier per chunk (dbuf)

        if (cg == 0 && tid < CHUNK) {       // presence (LDS byte, races benign)
            int la = labL[cur][tid];
            if ((unsigned)la < (unsigned)K_PAD) pres[la] = 1;
        }

        #pragma unroll
        for (int kk = 0; kk < 2; ++kk) {
            const int ks = 2 * kh + kk;
            const int* lp = &labL[cur][ks * 32 + g * 8];
            const int la0 = lp[0], la1 = lp[1], la2 = lp[2], la3 = lp[3];
            const int la4 = lp[4], la5 = lp[5], la6 = lp[6], la7 = lp[7];
            const short8 bfrag = *reinterpret_cast<const short8*>(
                &Bf[cur][(ct * 16 + rowid) * LROW + ks * 32 + g * 8]);
            #pragma unroll
            for (int m = 0; m < MT; ++m) {
                const int tgt = m * 16 + rowid;
                unsigned w0 = (la0 == tgt ? 0x3F80u : 0u) | (la1 == tgt ? 0x3F800000u : 0u);
                unsigned w1 = (la2 == tgt ? 0x3F80u : 0u) | (la3 == tgt ? 0x3F800000u : 0u);
                unsigned w2 = (la4 == tgt ? 0x3F80u : 0u) | (la5 == tgt ? 0x3F800000u : 0u);
                unsigned w3 = (la6 == tgt ? 0x3F80u : 0u) | (la7 == tgt ? 0x3F800000u : 0u);
                uint4 aw = make_uint4(w0, w1, w2, w3);
                short8 afrag = __builtin_bit_cast(short8, aw);
                acc[m] = __builtin_amdgcn_mfma_f32_16x16x32_bf16(afrag, bfrag, acc[m], 0, 0, 0);
            }
        }
    }

    __syncthreads();
    if (kh == 1) {
        #pragma unroll
        for (int m = 0; m < MT; ++m)
            #pragma unroll
            for (int r = 0; r < 4; ++r)
                fscr[ct][(m * 16 + g * 4 + r) * 16 + rowid] = acc[m][r];
    }
    __syncthreads();
    if (kh == 0) {
        float* dst = partial + (size_t)pb * K_PAD * C + cg * CPB + ct * 16 + rowid;
        #pragma unroll
        for (int m = 0; m < MT; ++m)
            #pragma unroll
            for (int r = 0; r < 4; ++r) {
                const int cls = m * 16 + g * 4 + r;
                dst[(size_t)cls * C] = acc[m][r] + fscr[ct][cls * 16 + rowid];
            }
    }
    if (cg == 0) {
        for (int i = tid; i < K_PAD; i += THR)
            if (pres[i]) vmask[i] = 1.0f;   // same value from all blocks
    }
}

// ---------------------------------------------------------------------------
// tail: block k. Phase 1: reduce partial row k over NPB slots + L2-normalize
// (count-divide cancels under normalization). Phase 2: sweep text rows with
// fused text-norm + online logsumexp (4 rows/wave). Ticket: last block
// computes n_valid from vmask and writes the output scalar.
// ---------------------------------------------------------------------------
__global__ __launch_bounds__(256) void tail_kernel(
    const float* __restrict__ partial,    // [NPB][K_PAD][C]
    const float* __restrict__ text,       // [K][C]
    const float* __restrict__ vmask,      // [K_PAD]
    float* __restrict__ loss_acc,
    unsigned int* __restrict__ ticket,
    float* __restrict__ out,
    int K, int C, int nblocks)
{
    __shared__ float ph[256];
    __shared__ float vm[K_PAD];
    __shared__ float red[5];
    __shared__ float wred[12];
    __shared__ unsigned int lastflag;

    const int k    = blockIdx.x;
    const int tid  = threadIdx.x;
    const int wid  = tid >> 6;
    const int lane = tid & 63;

    if (tid < K_PAD) vm[tid] = vmask[tid];
    __syncthreads();
    const bool valid = (vm[k] > 0.f);

    float contrib = 0.f;
    if (valid) {
        // phase 1: 64-slot reduce (8 independent chains) + normalize
        const size_t gs = (size_t)K_PAD * C;
        const float* pp = partial + (size_t)k * C + tid;   // C==256==blockDim
        float a0 = 0.f, a1 = 0.f, a2 = 0.f, a3 = 0.f;
        float a4 = 0.f, a5 = 0.f, a6 = 0.f, a7 = 0.f;
        for (int g = 0; g < NPB; g += 8) {
            a0 += pp[(g + 0) * gs]; a1 += pp[(g + 1) * gs];
            a2 += pp[(g + 2) * gs]; a3 += pp[(g + 3) * gs];
            a4 += pp[(g + 4) * gs]; a5 += pp[(g + 5) * gs];
            a6 += pp[(g + 6) * gs]; a7 += pp[(g + 7) * gs];
        }
        float sums = (((a0 + a1) + (a2 + a3)) + ((a4 + a5) + (a6 + a7)));

        float v = sums * sums;
        #pragma unroll
        for (int o = 32; o > 0; o >>= 1) v += __shfl_down(v, o);
        if (lane == 0) red[wid] = v;
        __syncthreads();
        if (tid == 0) {
            float s = red[0] + red[1] + red[2] + red[3];
            red[4] = 1.0f / fmaxf(sqrtf(s), EPSV);
        }
        __syncthreads();
        ph[tid] = sums * red[4];
        __syncthreads();

        // phase 2: 10 groups x (4 waves x 4 rows), fused text-norm
        float m = -INFINITY, s = 0.f, skk = 0.f;
        #pragma unroll 1
        for (int gq = 0; gq < K_PAD / 16; ++gq) {
            const int j0 = gq * 16 + wid * 4;
            const float* t0 = text + (size_t)(j0 + 0 < K ? j0 + 0 : K - 1) * C;
            const float* t1 = text + (size_t)(j0 + 1 < K ? j0 + 1 : K - 1) * C;
            const float* t2 = text + (size_t)(j0 + 2 < K ? j0 + 2 : K - 1) * C;
            const float* t3 = text + (size_t)(j0 + 3 < K ? j0 + 3 : K - 1) * C;
            float d0 = 0.f, d1 = 0.f, d2 = 0.f, d3 = 0.f;
            float q0 = 0.f, q1 = 0.f, q2 = 0.f, q3 = 0.f;
            #pragma unroll
            for (int cc = lane; cc < 256; cc += 64) {
                float p  = ph[cc];
                float x0 = t0[cc], x1 = t1[cc], x2 = t2[cc], x3 = t3[cc];
                d0 = fmaf(p, x0, d0);  q0 = fmaf(x0, x0, q0);
                d1 = fmaf(p, x1, d1);  q1 = fmaf(x1, x1, q1);
                d2 = fmaf(p, x2, d2);  q2 = fmaf(x2, x2, q2);
                d3 = fmaf(p, x3, d3);  q3 = fmaf(x3, x3, q3);
            }
            #pragma unroll
            for (int o = 32; o > 0; o >>= 1) {
                d0 += __shfl_down(d0, o); d1 += __shfl_down(d1, o);
                d2 += __shfl_down(d2, o); d3 += __shfl_down(d3, o);
                q0 += __shfl_down(q0, o); q1 += __shfl_down(q1, o);
                q2 += __shfl_down(q2, o); q3 += __shfl_down(q3, o);
            }
            if (lane == 0) {
                float dd[4] = {d0, d1, d2, d3};
                float qq[4] = {q0, q1, q2, q3};
                #pragma unroll
                for (int r = 0; r < 4; ++r) {
                    int j = j0 + r;
                    float vmj = vm[j];
                    float sim = dd[r] * (10.0f / fmaxf(sqrtf(qq[r]), EPSV));
                    float ms  = vmj * sim - (1.f - vmj) * 1e9f;
                    if (j == k) skk = ms;
                    if (ms > m) { s = s * expf(m - ms) + 1.f; m = ms; }
                    else        { s += expf(ms - m); }
                }
            }
        }
        if (lane == 0) { wred[wid*3+0] = m; wred[wid*3+1] = s; wred[wid*3+2] = skk; }
        __syncthreads();
        if (tid == 0) {
            float M = fmaxf(fmaxf(wred[0], wred[3]), fmaxf(wred[6], wred[9]));
            float S = 0.f, SKK = 0.f;
            #pragma unroll
            for (int ww = 0; ww < 4; ++ww) {
                S   += wred[ww*3+1] * expf(wred[ww*3+0] - M);
                SKK += wred[ww*3+2];          // non-owners contributed 0
            }
            contrib = M + logf(S) - SKK;      // -logp[k][k]
        }
    }

    // ticket: loss atomic, fence, last block finalizes
    if (tid == 0) {
        if (valid) atomicAdd(loss_acc, contrib);
        __threadfence();
        unsigned old = atomicAdd(ticket, 1u);
        lastflag = (old == (unsigned)(nblocks - 1)) ? 1u : 0u;
    }
    __syncthreads();
    if (lastflag) {
        float v = (tid < K_PAD) ? vm[tid] : 0.f;
        #pragma unroll
        for (int o = 32; o > 0; o >>= 1) v += __shfl_down(v, o);
        if (lane == 0) red[wid] = v;
        __syncthreads();
        if (tid == 0) {
            float nv = red[0] + red[1] + red[2] + red[3];
            float total = atomicAdd(loss_acc, 0.0f);   // device-scope read
            out[0] = (nv > 1.f) ? total / fmaxf(nv, 1.f) : 0.f;
        }
    }
}

extern "C" void kernel_launch(void* const* d_in, const int* in_sizes, int n_in,
                              void* d_out, int out_size, void* d_ws, size_t ws_size,
                              hipStream_t stream) {
    const float* feat   = (const float*)d_in[0];
    const int*   labels = (const int*)d_in[1];
    const float* text   = (const float*)d_in[2];
    const int*   ign    = (const int*)d_in[3];

    const int B  = 8;
    const int N  = in_sizes[1];          // 131072
    const int HW = N / B;                // 16384
    const int C  = in_sizes[0] / N;      // 256
    const int K  = in_sizes[2] / C;      // 150

    // workspace: partial [NPB][K_PAD][C] (fully overwritten) | vmask | acc | ticket
    float*        partial  = (float*)d_ws;
    float*        vmask    = partial + (size_t)NPB * K_PAD * C;
    float*        loss_acc = vmask + K_PAD;
    unsigned int* ticket   = (unsigned int*)(loss_acc + 1);

    hipMemsetAsync(vmask, 0, (K_PAD + 2) * sizeof(float), stream);

    protomm_kernel<<<NPB * 4, THR, 0, stream>>>(
        feat, labels, ign, partial, vmask, C, HW);

    tail_kernel<<<K, 256, 0, stream>>>(
        partial, text, vmask, loss_acc, ticket, (float*)d_out, K, C, K);
}

// Round 7
// 66.323 us; speedup vs baseline: 3.9733x; 1.0548x over previous
//
#include <hip/hip_runtime.h>
#include <math.h>

#define EPSV 1e-12f

typedef __attribute__((ext_vector_type(8))) short short8;
typedef __attribute__((ext_vector_type(4))) float f32x4;

constexpr int MT    = 10;            // M-tiles of 16 -> K_PAD = 160 class rows
constexpr int K_PAD = MT * 16;
constexpr int CPB   = 64;            // channels per block
constexpr int CHUNK = 128;           // pixels per staged chunk
constexpr int PBPX  = 1024;          // pixels per pixel-block (2 blocks/CU)
constexpr int NCHK  = PBPX / CHUNK;  // 8 chunks
constexpr int NPB   = 128;           // pixel-blocks (131072/1024)
constexpr int THR   = 512;           // 8 waves
constexpr int LROW  = 136;           // LDS B-row stride in shorts
constexpr int FROW  = 68;            // fscr row stride (floats)

__device__ __forceinline__ unsigned short f2bf(float f) {
    unsigned u = __builtin_bit_cast(unsigned, f);
    return (unsigned short)((u + 0x7FFFu + ((u >> 16) & 1u)) >> 16);  // RNE
}

// ---------------------------------------------------------------------------
// protomm: segment-sum via one-hot MFMA GEMM.
// Wave mapping: w = (q, kh); wave owns m-subset {q, q+4, q+8} (classes) for
// ALL 4 channel tiles -> A-frag built once per (m,kstep) (4x less VALU than
// per-ct waves). Double-buffered staging, 2 blocks/CU.
// ---------------------------------------------------------------------------
__global__ __launch_bounds__(THR, 4) void protomm_kernel(
    const float* __restrict__ feat,     // [B,C,HW]
    const int*   __restrict__ labels,   // [B,HW]
    const int*   __restrict__ ign_p,
    float*       __restrict__ partial,  // [NPB][K_PAD][C]
    float*       __restrict__ vmask,    // [K_PAD] pre-zeroed
    int C, int HW)
{
    __shared__ unsigned short Bf[2][CPB * LROW];   // 34.8 KB
    __shared__ int   labL[2][CHUNK];               // 1 KB
    __shared__ float fscr[K_PAD * FROW];           // 43.5 KB
    __shared__ unsigned char pres[K_PAD];

    const int tid   = threadIdx.x;
    const int w     = tid >> 6;
    const int l     = tid & 63;
    const int q     = w & 3;        // m-subset selector
    const int kh    = w >> 2;       // k-half
    const int rowid = l & 15;
    const int g     = l >> 4;

    const int bid = blockIdx.x;
    const int cg  = bid & 3;
    const int pb  = bid >> 2;
    const int b   = pb >> 4;
    const int px0 = (pb & 15) * PBPX;
    const int ig  = *ign_p;

    const int qq  = tid & 31;
    const int chp = tid >> 5;
    const float* fb = feat + ((size_t)(b * C + cg * CPB + chp)) * HW + px0 + 4 * qq;
    const int*   lb = labels + (size_t)b * HW + px0;

    if (cg == 0)
        for (int i = tid; i < K_PAD; i += THR) pres[i] = 0;

    f32x4 acc[3][4];
    #pragma unroll
    for (int mi = 0; mi < 3; ++mi)
        #pragma unroll
        for (int ct = 0; ct < 4; ++ct)
            acc[mi][ct] = (f32x4){0.f, 0.f, 0.f, 0.f};

    float4 pf0, pf1, pf2, pf3;
    int4   plab;
    auto issue = [&](int ck) {
        const float* p = fb + ck * CHUNK;
        pf0 = *reinterpret_cast<const float4*>(p);
        pf1 = *reinterpret_cast<const float4*>(p + (size_t)16 * HW);
        pf2 = *reinterpret_cast<const float4*>(p + (size_t)32 * HW);
        pf3 = *reinterpret_cast<const float4*>(p + (size_t)48 * HW);
        if (tid < 32)
            plab = *reinterpret_cast<const int4*>(lb + ck * CHUNK + 4 * tid);
    };
    auto commit = [&](int buf) {
        float4 v[4] = {pf0, pf1, pf2, pf3};
        #pragma unroll
        for (int i = 0; i < 4; ++i) {
            unsigned* dst = reinterpret_cast<unsigned*>(
                &Bf[buf][(chp + 16 * i) * LROW + 4 * qq]);
            dst[0] = (unsigned)f2bf(v[i].x) | ((unsigned)f2bf(v[i].y) << 16);
            dst[1] = (unsigned)f2bf(v[i].z) | ((unsigned)f2bf(v[i].w) << 16);
        }
        if (tid < 32) {
            int4 lv = plab;
            lv.x = (lv.x == ig) ? 0 : lv.x;
            lv.y = (lv.y == ig) ? 0 : lv.y;
            lv.z = (lv.z == ig) ? 0 : lv.z;
            lv.w = (lv.w == ig) ? 0 : lv.w;
            *reinterpret_cast<int4*>(&labL[buf][4 * tid]) = lv;
        }
    };

    issue(0);

    for (int ck = 0; ck < NCHK; ++ck) {
        const int cur = ck & 1;
        commit(cur);                        // vmcnt wait for chunk ck loads
        if (ck + 1 < NCHK) issue(ck + 1);   // next chunk in flight under MFMA
        __syncthreads();

        if (cg == 0 && tid < CHUNK) {       // presence bytes (races benign)
            int la = labL[cur][tid];
            if ((unsigned)la < (unsigned)K_PAD) pres[la] = 1;
        }

        #pragma unroll
        for (int kk = 0; kk < 2; ++kk) {
            const int ks = 2 * kh + kk;
            const int4 lA = *reinterpret_cast<const int4*>(&labL[cur][ks * 32 + g * 8]);
            const int4 lB = *reinterpret_cast<const int4*>(&labL[cur][ks * 32 + g * 8 + 4]);
            short8 bfragv[4];
            #pragma unroll
            for (int ct = 0; ct < 4; ++ct)
                bfragv[ct] = *reinterpret_cast<const short8*>(
                    &Bf[cur][(ct * 16 + rowid) * LROW + ks * 32 + g * 8]);
            #pragma unroll
            for (int mi = 0; mi < 3; ++mi) {
                const int m = q + 4 * mi;
                if (m < MT) {
                    const int tgt = m * 16 + rowid;
                    unsigned w0 = (lA.x == tgt ? 0x3F80u : 0u) | (lA.y == tgt ? 0x3F800000u : 0u);
                    unsigned w1 = (lA.z == tgt ? 0x3F80u : 0u) | (lA.w == tgt ? 0x3F800000u : 0u);
                    unsigned w2 = (lB.x == tgt ? 0x3F80u : 0u) | (lB.y == tgt ? 0x3F800000u : 0u);
                    unsigned w3 = (lB.z == tgt ? 0x3F80u : 0u) | (lB.w == tgt ? 0x3F800000u : 0u);
                    uint4 aw = make_uint4(w0, w1, w2, w3);
                    short8 afrag = __builtin_bit_cast(short8, aw);
                    #pragma unroll
                    for (int ct = 0; ct < 4; ++ct)
                        acc[mi][ct] = __builtin_amdgcn_mfma_f32_16x16x32_bf16(
                            afrag, bfragv[ct], acc[mi][ct], 0, 0, 0);
                }
            }
        }
    }

    // flush: kh=1 waves park in fscr, kh=0 waves add + store to partial
    __syncthreads();
    if (kh == 1) {
        #pragma unroll
        for (int mi = 0; mi < 3; ++mi) {
            const int m = q + 4 * mi;
            if (m < MT)
                #pragma unroll
                for (int ct = 0; ct < 4; ++ct)
                    #pragma unroll
                    for (int r = 0; r < 4; ++r)
                        fscr[(m * 16 + g * 4 + r) * FROW + ct * 16 + rowid] = acc[mi][ct][r];
        }
    }
    __syncthreads();
    if (kh == 0) {
        float* dst = partial + (size_t)pb * K_PAD * C + cg * CPB;
        #pragma unroll
        for (int mi = 0; mi < 3; ++mi) {
            const int m = q + 4 * mi;
            if (m < MT)
                #pragma unroll
                for (int ct = 0; ct < 4; ++ct)
                    #pragma unroll
                    for (int r = 0; r < 4; ++r) {
                        const int cls = m * 16 + g * 4 + r;
                        const int col = ct * 16 + rowid;
                        dst[(size_t)cls * C + col] =
                            acc[mi][ct][r] + fscr[cls * FROW + col];
                    }
        }
    }
    if (cg == 0) {
        for (int i = tid; i < K_PAD; i += THR)
            if (pres[i]) vmask[i] = 1.0f;
    }
}

// ---------------------------------------------------------------------------
// tail: block k. Phase 1: float4 reduce of partial row k over NPB slots
// (8 chains, 4 slot-groups) + L2-normalize (count cancels). Phase 2: text
// sweep, float4 loads, fused text-norm + online logsumexp. Ticket finalize.
// ---------------------------------------------------------------------------
__global__ __launch_bounds__(256) void tail_kernel(
    const float* __restrict__ partial,    // [NPB][K_PAD][C]
    const float* __restrict__ text,       // [K][C]
    const float* __restrict__ vmask,      // [K_PAD]
    float* __restrict__ loss_acc,
    unsigned int* __restrict__ ticket,
    float* __restrict__ out,
    int K, int C, int nblocks)
{
    __shared__ float ph[256];
    __shared__ float scr[4][260];
    __shared__ float vm[K_PAD];
    __shared__ float red[5];
    __shared__ float wred[12];
    __shared__ unsigned int lastflag;

    const int k    = blockIdx.x;
    const int tid  = threadIdx.x;
    const int wid  = tid >> 6;
    const int lane = tid & 63;

    if (tid < K_PAD) vm[tid] = vmask[tid];
    __syncthreads();
    const bool valid = (vm[k] > 0.f);

    float contrib = 0.f;
    if (valid) {
        // phase 1: thread (sg, cq) reduces slots s == sg (mod 4), channel quad cq
        const int cq = tid & 63;
        const int sg = tid >> 6;
        const size_t gs = (size_t)K_PAD * C;
        const float* pbase = partial + (size_t)k * C + 4 * cq;
        float4 a0 = {0,0,0,0}, a1 = {0,0,0,0}, a2 = {0,0,0,0}, a3 = {0,0,0,0};
        float4 a4 = {0,0,0,0}, a5 = {0,0,0,0}, a6 = {0,0,0,0}, a7 = {0,0,0,0};
        for (int s = sg; s < NPB; s += 32) {
            a0 += *(const float4*)(pbase + (size_t)(s +  0) * gs);
            a1 += *(const float4*)(pbase + (size_t)(s +  4) * gs);
            a2 += *(const float4*)(pbase + (size_t)(s +  8) * gs);
            a3 += *(const float4*)(pbase + (size_t)(s + 12) * gs);
            a4 += *(const float4*)(pbase + (size_t)(s + 16) * gs);
            a5 += *(const float4*)(pbase + (size_t)(s + 20) * gs);
            a6 += *(const float4*)(pbase + (size_t)(s + 24) * gs);
            a7 += *(const float4*)(pbase + (size_t)(s + 28) * gs);
        }
        float4 asum = (((a0 + a1) + (a2 + a3)) + ((a4 + a5) + (a6 + a7)));
        *(float4*)&scr[sg][4 * cq] = asum;
        __syncthreads();
        float val = scr[0][tid] + scr[1][tid] + scr[2][tid] + scr[3][tid];

        float v = val * val;
        #pragma unroll
        for (int o = 32; o > 0; o >>= 1) v += __shfl_down(v, o);
        if (lane == 0) red[wid] = v;
        __syncthreads();
        if (tid == 0) {
            float s = red[0] + red[1] + red[2] + red[3];
            red[4] = 1.0f / fmaxf(sqrtf(s), EPSV);
        }
        __syncthreads();
        ph[tid] = val * red[4];
        __syncthreads();

        // phase 2: 10 groups x (4 waves x 4 rows); float4 loads, fused norm
        const float4 pv = *(const float4*)&ph[4 * lane];
        float m = -INFINITY, s = 0.f, skk = 0.f;
        #pragma unroll 1
        for (int gq = 0; gq < K_PAD / 16; ++gq) {
            const int j0 = gq * 16 + wid * 4;
            const float4* t0 = (const float4*)(text + (size_t)(j0 + 0 < K ? j0 + 0 : 0) * C);
            const float4* t1 = (const float4*)(text + (size_t)(j0 + 1 < K ? j0 + 1 : 0) * C);
            const float4* t2 = (const float4*)(text + (size_t)(j0 + 2 < K ? j0 + 2 : 0) * C);
            const float4* t3 = (const float4*)(text + (size_t)(j0 + 3 < K ? j0 + 3 : 0) * C);
            float4 x0 = t0[lane], x1 = t1[lane], x2 = t2[lane], x3 = t3[lane];
            float d0 = pv.x*x0.x + pv.y*x0.y + pv.z*x0.z + pv.w*x0.w;
            float q0 = x0.x*x0.x + x0.y*x0.y + x0.z*x0.z + x0.w*x0.w;
            float d1 = pv.x*x1.x + pv.y*x1.y + pv.z*x1.z + pv.w*x1.w;
            float q1 = x1.x*x1.x + x1.y*x1.y + x1.z*x1.z + x1.w*x1.w;
            float d2 = pv.x*x2.x + pv.y*x2.y + pv.z*x2.z + pv.w*x2.w;
            float q2 = x2.x*x2.x + x2.y*x2.y + x2.z*x2.z + x2.w*x2.w;
            float d3 = pv.x*x3.x + pv.y*x3.y + pv.z*x3.z + pv.w*x3.w;
            float q3 = x3.x*x3.x + x3.y*x3.y + x3.z*x3.z + x3.w*x3.w;
            #pragma unroll
            for (int o = 32; o > 0; o >>= 1) {
                d0 += __shfl_down(d0, o); d1 += __shfl_down(d1, o);
                d2 += __shfl_down(d2, o); d3 += __shfl_down(d3, o);
                q0 += __shfl_down(q0, o); q1 += __shfl_down(q1, o);
                q2 += __shfl_down(q2, o); q3 += __shfl_down(q3, o);
            }
            if (lane == 0) {
                float dd[4] = {d0, d1, d2, d3};
                float qq[4] = {q0, q1, q2, q3};
                #pragma unroll
                for (int r = 0; r < 4; ++r) {
                    int j = j0 + r;
                    float vmj = (j < K_PAD) ? vm[j] : 0.f;
                    float sim = dd[r] * (10.0f / fmaxf(sqrtf(qq[r]), EPSV));
                    float ms  = vmj * sim - (1.f - vmj) * 1e9f;
                    if (j == k) skk = ms;
                    if (ms > m) { s = s * __expf(m - ms) + 1.f; m = ms; }
                    else        { s += __expf(ms - m); }
                }
            }
        }
        if (lane == 0) { wred[wid*3+0] = m; wred[wid*3+1] = s; wred[wid*3+2] = skk; }
        __syncthreads();
        if (tid == 0) {
            float M = fmaxf(fmaxf(wred[0], wred[3]), fmaxf(wred[6], wred[9]));
            float S = 0.f, SKK = 0.f;
            #pragma unroll
            for (int ww = 0; ww < 4; ++ww) {
                S   += wred[ww*3+1] * __expf(wred[ww*3+0] - M);
                SKK += wred[ww*3+2];
            }
            contrib = M + logf(S) - SKK;      // -logp[k][k]
        }
    }

    // ticket: loss atomic, fence, last block finalizes
    if (tid == 0) {
        if (valid) atomicAdd(loss_acc, contrib);
        __threadfence();
        unsigned old = atomicAdd(ticket, 1u);
        lastflag = (old == (unsigned)(nblocks - 1)) ? 1u : 0u;
    }
    __syncthreads();
    if (lastflag) {
        float v = (tid < K_PAD) ? vm[tid] : 0.f;
        #pragma unroll
        for (int o = 32; o > 0; o >>= 1) v += __shfl_down(v, o);
        if (lane == 0) red[wid] = v;
        __syncthreads();
        if (tid == 0) {
            float nv = red[0] + red[1] + red[2] + red[3];
            float total = atomicAdd(loss_acc, 0.0f);   // device-scope read
            out[0] = (nv > 1.f) ? total / fmaxf(nv, 1.f) : 0.f;
        }
    }
}

extern "C" void kernel_launch(void* const* d_in, const int* in_sizes, int n_in,
                              void* d_out, int out_size, void* d_ws, size_t ws_size,
                              hipStream_t stream) {
    const float* feat   = (const float*)d_in[0];
    const int*   labels = (const int*)d_in[1];
    const float* text   = (const float*)d_in[2];
    const int*   ign    = (const int*)d_in[3];

    const int B  = 8;
    const int N  = in_sizes[1];          // 131072
    const int HW = N / B;                // 16384
    const int C  = in_sizes[0] / N;      // 256
    const int K  = in_sizes[2] / C;      // 150

    // workspace: partial [NPB][K_PAD][C] (fully overwritten) | vmask | acc | ticket
    float*        partial  = (float*)d_ws;
    float*        vmask    = partial + (size_t)NPB * K_PAD * C;
    float*        loss_acc = vmask + K_PAD;
    unsigned int* ticket   = (unsigned int*)(loss_acc + 1);

    hipMemsetAsync(vmask, 0, (K_PAD + 2) * sizeof(float), stream);

    protomm_kernel<<<NPB * 4, THR, 0, stream>>>(
        feat, labels, ign, partial, vmask, C, HW);

    tail_kernel<<<K, 256, 0, stream>>>(
        partial, text, vmask, loss_acc, ticket, (float*)d_out, K, C, K);
}